// Round 2
// 131.830 us; speedup vs baseline: 1.0401x; 1.0401x over previous
//
#include <hip/hip_runtime.h>
#include <stdint.h>

#define N_WORDS 8192
#define LOG2E_8 0.18033688011112043f   // log2(e)/sqrt(64)

typedef __attribute__((ext_vector_type(8))) short short8;
typedef __attribute__((ext_vector_type(4))) float f32x4;
typedef __attribute__((ext_vector_type(2))) __fp16 pkhalf2;   // cvt_pkrtz return type
typedef __attribute__((ext_vector_type(4))) _Float16 half4;
typedef __attribute__((ext_vector_type(8))) _Float16 half8;

__device__ __forceinline__ unsigned short f32_to_bf16(float f) {
    union { float f; unsigned u; } v; v.f = f;
    unsigned u = v.u;
    return (unsigned short)((u + 0x7FFFu + ((u >> 16) & 1u)) >> 16);
}

__device__ __forceinline__ unsigned short f32_to_f16(float f) {
    union { _Float16 h; unsigned short u; } cv;
    cv.h = (_Float16)f;
    return cv.u;
}

// global -> LDS direct copy, 16B per lane. LDS dest must be wave-uniform base;
// HW adds lane*16. Global ptr is per-lane.
__device__ __forceinline__ void async16(const void* g, void* l) {
    __builtin_amdgcn_global_load_lds(
        (const __attribute__((address_space(1))) unsigned int*)g,
        (__attribute__((address_space(3))) unsigned int*)l, 16, 0, 0);
}

// ---------------------------------------------------------------------------
// Kernel 1: QKV projection as bf16 MFMA GEMM: [8192x512] @ [512x64] x3 mats,
// plus (blockIdx.y==3) the w_o_eff fold: we[p][j] = sum_h wo[h*64+p][j].
// grid (128, 4), 256 thr -> exactly 512 blocks = 2/CU (balanced).
// Register-prefetch pipeline: global loads for tile kb+1 issued while MFMAs
// of tile kb run, so staging latency hides under compute.
// Outputs:
//   mat0 -> qB bf16 [row][64], cols XOR-swizzled in 8-elem chunks, pre-scaled
//           by log2e/8 (folds softmax scale + exp2 base change)
//   mat1 -> kB bf16, same swizzle
//   mat2 -> vH f16 [vcol][8192], rows swizzled per 64-row group
// Swizzle: chunk c (8 elems) of row r stored at position c ^ (r&7).
// ---------------------------------------------------------------------------
__global__ __launch_bounds__(256) void qkv_gemm(
    const float* __restrict__ x,
    const float* __restrict__ wq, const float* __restrict__ wk,
    const float* __restrict__ wv, const float* __restrict__ wo,
    unsigned short* __restrict__ qB, unsigned short* __restrict__ kB,
    unsigned short* __restrict__ vH, float* __restrict__ we)
{
    int t = threadIdx.x;
    int mat = blockIdx.y;

    if (mat == 3) {
        // w_o_eff fold (was a separate launch)
        int i = blockIdx.x * 256 + t;
        int p = i >> 9;
        int j = i & 511;
        float s = 0.0f;
#pragma unroll
        for (int h = 0; h < 8; ++h) s += wo[(size_t)(h * 64 + p) * 512 + j];
        we[i] = s;
        return;
    }

    __shared__ __align__(16) unsigned short ldsX[64 * 72];  // [m][k] pitch 72
    __shared__ __align__(16) unsigned short ldsW[64 * 72];  // [n][k] pitch 72

    int mt = blockIdx.x;
    const float* w = (mat == 0) ? wq : (mat == 1) ? wk : wv;

    int wvid = t >> 6, lane = t & 63;
    int lq = lane & 15, quad = lane >> 4;

    f32x4 acc[4];
#pragma unroll
    for (int nt = 0; nt < 4; ++nt) acc[nt] = (f32x4){0.f, 0.f, 0.f, 0.f};

    // prefetch registers
    float4 xr[4];
    float wr[16];
    int wn = t & 63, wkbs = (t >> 6) * 16;

    // prologue: load tile kb=0
    {
        int k0 = 0;
#pragma unroll
        for (int j2 = 0; j2 < 4; ++j2) {
            int i = t + j2 * 256;
            int row = i >> 4, c4 = (i & 15) * 4;
            xr[j2] = *(const float4*)(x + (size_t)(mt * 64 + row) * 512 + k0 + c4);
        }
#pragma unroll
        for (int kk = 0; kk < 16; ++kk)
            wr[kk] = w[(size_t)(k0 + wkbs + kk) * 64 + wn];
    }

    for (int kb = 0; kb < 8; ++kb) {
        __syncthreads();   // all waves finished reading LDS of previous tile
        // store prefetched registers -> LDS (f32 -> bf16)
#pragma unroll
        for (int j2 = 0; j2 < 4; ++j2) {
            int i = t + j2 * 256;
            int row = i >> 4, c4 = (i & 15) * 4;
            unsigned p0 = f32_to_bf16(xr[j2].x) | ((unsigned)f32_to_bf16(xr[j2].y) << 16);
            unsigned p1 = f32_to_bf16(xr[j2].z) | ((unsigned)f32_to_bf16(xr[j2].w) << 16);
            *(uint2*)(&ldsX[row * 72 + c4]) = make_uint2(p0, p1);
        }
#pragma unroll
        for (int kk = 0; kk < 16; kk += 2) {
            unsigned p = f32_to_bf16(wr[kk]) | ((unsigned)f32_to_bf16(wr[kk + 1]) << 16);
            *(unsigned*)(&ldsW[wn * 72 + wkbs + kk]) = p;
        }
        __syncthreads();

        // issue next tile's global loads early; they complete under the MFMAs
        if (kb < 7) {
            int k0 = (kb + 1) * 64;
#pragma unroll
            for (int j2 = 0; j2 < 4; ++j2) {
                int i = t + j2 * 256;
                int row = i >> 4, c4 = (i & 15) * 4;
                xr[j2] = *(const float4*)(x + (size_t)(mt * 64 + row) * 512 + k0 + c4);
            }
#pragma unroll
            for (int kk = 0; kk < 16; ++kk)
                wr[kk] = w[(size_t)(k0 + wkbs + kk) * 64 + wn];
        }

        int m = wvid * 16 + lq;
        short8 a0 = *(const short8*)(&ldsX[m * 72 + quad * 8]);
        short8 a1 = *(const short8*)(&ldsX[m * 72 + 32 + quad * 8]);
#pragma unroll
        for (int nt = 0; nt < 4; ++nt) {
            short8 b0 = *(const short8*)(&ldsW[(nt * 16 + lq) * 72 + quad * 8]);
            short8 b1 = *(const short8*)(&ldsW[(nt * 16 + lq) * 72 + 32 + quad * 8]);
            acc[nt] = __builtin_amdgcn_mfma_f32_16x16x32_bf16(a0, b0, acc[nt], 0, 0, 0);
            acc[nt] = __builtin_amdgcn_mfma_f32_16x16x32_bf16(a1, b1, acc[nt], 0, 0, 0);
        }
    }

    int mrow_base = mt * 64 + wvid * 16;
#pragma unroll
    for (int nt = 0; nt < 4; ++nt) {
#pragma unroll
        for (int r = 0; r < 4; ++r) {
            int row = mrow_base + quad * 4 + r;
            int n = nt * 16 + lq;
            float v = acc[nt][r];
            if (mat == 0) {
                v *= LOG2E_8;
                int col = ((((n >> 3) ^ (row & 7)) << 3)) | (n & 7);
                qB[(size_t)row * 64 + col] = f32_to_bf16(v);
            } else if (mat == 1) {
                int col = ((((n >> 3) ^ (row & 7)) << 3)) | (n & 7);
                kB[(size_t)row * 64 + col] = f32_to_bf16(v);
            } else {
                int rs = (row & ~63) | (((((row >> 3) & 7) ^ (n & 7)) << 3)) | (row & 7);
                vH[(size_t)n * N_WORDS + rs] = f32_to_f16(v);
            }
        }
    }
}

// ---------------------------------------------------------------------------
// Kernel 2: fixed-max flash attention partials.
// grid (64 q-blocks of 128 rows, S splits), 256 thr = 4 waves x 32 qrows.
// Double-buffered K/V staging (64 KB LDS, 2 blocks/CU): tile t+1's
// global_load_lds issued right after the barrier, drains at the NEXT
// barrier -- load latency hides under the whole compute phase.
// S^T = K.Q^T with 16x16x32 bf16 MFMA; its C-layout (qrow=lane&15,
// krow=quad*4+r) feeds PV directly.
// PV uses 16x16x32 f16 (K=32) with a PERMUTED logical-k mapping:
//   logical k = quad*8+j  <->  physical krow = 16h + quad*4 + (j&3), h=j>>2.
// A = concat(p from S^T at nt=2u, nt=2u+1); B = concat of the two half4 V
// loads -- both sides use the same permutation, so no cross-lane shuffles.
// This halves PV MFMA issue slots vs the legacy 16x16x16 shape.
// lsum is computed by one extra K=32 MFMA against a ones vector (replaces
// 16 VALU adds per pair + the shuffle epilogue), and numerator/denominator
// use identical f16-rounded p (rtz bias cancels in the ratio).
// ---------------------------------------------------------------------------
__global__ __launch_bounds__(256) void attn_kernel(
    const unsigned short* __restrict__ qB,
    const unsigned short* __restrict__ kB,
    const unsigned short* __restrict__ vH,
    float* __restrict__ pO, float* __restrict__ pl, int nk)
{
    __shared__ __align__(16) unsigned short ldsK[2][128 * 64];
    __shared__ __align__(16) unsigned short ldsV[2][64 * 128];

    int t = threadIdx.x;
    int wvid = t >> 6, lane = t & 63;
    int lq = lane & 15, quad = lane >> 4;
    int mbase = blockIdx.x * 128 + wvid * 32;
    int n0 = blockIdx.y * nk;

    // Q fragments for 2 q-subtiles (rows mbase+lq, mbase+16+lq)
    short8 qf[2][2];
#pragma unroll
    for (int qs = 0; qs < 2; ++qs) {
        int row = mbase + qs * 16 + lq;
        const unsigned short* qr = qB + (size_t)row * 64;
        int s7 = row & 7;
        qf[qs][0] = *(const short8*)(qr + ((quad ^ s7) << 3));
        qf[qs][1] = *(const short8*)(qr + (((4 + quad) ^ s7) << 3));
    }

    f32x4 oacc[2][4];
#pragma unroll
    for (int qs = 0; qs < 2; ++qs)
#pragma unroll
        for (int vt = 0; vt < 4; ++vt) oacc[qs][vt] = (f32x4){0.f, 0.f, 0.f, 0.f};
    f32x4 lacc[2];
    lacc[0] = (f32x4){0.f, 0.f, 0.f, 0.f};
    lacc[1] = (f32x4){0.f, 0.f, 0.f, 0.f};

    const half8 ones = {(_Float16)1.f, (_Float16)1.f, (_Float16)1.f, (_Float16)1.f,
                        (_Float16)1.f, (_Float16)1.f, (_Float16)1.f, (_Float16)1.f};

    auto stage = [&](int buf, int nb) {
        // K tile: 16KB contiguous in global (swizzle baked in)
        const char* gK = (const char*)kB + (size_t)nb * 128;
#pragma unroll
        for (int i = 0; i < 4; ++i) {
            int L0 = (wvid * 4 + i) * 64;
            async16(gK + (size_t)(L0 + lane) * 16, (char*)ldsK[buf] + (size_t)L0 * 16);
        }
        // V tile: 64 vcols x 128 krows (2 chunk-groups per vcol)
#pragma unroll
        for (int i = 0; i < 4; ++i) {
            int L0 = (wvid * 4 + i) * 64;
            int L = L0 + lane;
            int vcol = L >> 4, ct = L & 15;
            const char* src = (const char*)vH + (size_t)vcol * 16384 +
                              (size_t)nb * 2 + ((ct >> 3) << 7) + ((ct & 7) << 4);
            async16(src, (char*)ldsV[buf] + (size_t)L0 * 16);
        }
    };

    int tiles = nk >> 7;
    stage(0, n0);
    int cur = 0;

    for (int tt = 0; tt < tiles; ++tt) {
        __syncthreads();   // per-wave vmcnt(0) drain + barrier: buf[cur] ready,
                           // everyone done reading buf[cur^1]
        if (tt + 1 < tiles) stage(cur ^ 1, n0 + (tt + 1) * 128);

        __builtin_amdgcn_s_setprio(1);
        const unsigned short* K = ldsK[cur];
        const unsigned short* V = ldsV[cur];

#pragma unroll
        for (int u = 0; u < 4; ++u) {
            // S^T for the two 16-krow halves of this 32-krow pair
            f32x4 st[2][2];   // [h][qs]
#pragma unroll
            for (int h = 0; h < 2; ++h) {
                int nt = 2 * u + h;
                int s7 = lq & 7;
                const unsigned short* kr = K + (nt * 16 + lq) * 64;
                short8 a0 = *(const short8*)(kr + ((quad ^ s7) << 3));
                short8 a1 = *(const short8*)(kr + (((4 + quad) ^ s7) << 3));
                f32x4 s0 = (f32x4){0.f, 0.f, 0.f, 0.f};
                f32x4 s1 = (f32x4){0.f, 0.f, 0.f, 0.f};
                s0 = __builtin_amdgcn_mfma_f32_16x16x32_bf16(a0, qf[0][0], s0, 0, 0, 0);
                s0 = __builtin_amdgcn_mfma_f32_16x16x32_bf16(a1, qf[0][1], s0, 0, 0, 0);
                s1 = __builtin_amdgcn_mfma_f32_16x16x32_bf16(a0, qf[1][0], s1, 0, 0, 0);
                s1 = __builtin_amdgcn_mfma_f32_16x16x32_bf16(a1, qf[1][1], s1, 0, 0, 0);
                st[h][0] = s0;
                st[h][1] = s1;
            }

            // p = exp2(s); pack to f16 pairs (consistent num/denom rounding)
            union { half8 v8; pkhalf2 v2[4]; } pa[2];
#pragma unroll
            for (int qs = 0; qs < 2; ++qs) {
#pragma unroll
                for (int h = 0; h < 2; ++h) {
                    float e0 = exp2f(st[h][qs][0]);
                    float e1 = exp2f(st[h][qs][1]);
                    float e2 = exp2f(st[h][qs][2]);
                    float e3 = exp2f(st[h][qs][3]);
                    pa[qs].v2[h * 2 + 0] = __builtin_amdgcn_cvt_pkrtz(e0, e1);
                    pa[qs].v2[h * 2 + 1] = __builtin_amdgcn_cvt_pkrtz(e2, e3);
                }
                // lsum via MFMA against ones (D[qrow][*] = sum_k p)
                lacc[qs] = __builtin_amdgcn_mfma_f32_16x16x32_f16(
                    pa[qs].v8, ones, lacc[qs], 0, 0, 0);
            }

            // PV: one K=32 f16 MFMA per (qs, vt) covering both 16-krow halves
            int ct0 = 4 * u + (quad >> 1);
            int off = (quad & 1) * 4;
#pragma unroll
            for (int vt = 0; vt < 4; ++vt) {
                int vcol = vt * 16 + lq;
                int cs0 = (ct0 & 8) | ((ct0 & 7) ^ (vcol & 7));
                int ct1 = ct0 + 2;
                int cs1 = (ct1 & 8) | ((ct1 & 7) ^ (vcol & 7));
                union { half8 v8; half4 v4[2]; } vb;
                vb.v4[0] = *(const half4*)(V + vcol * 128 + (cs0 << 3) + off);
                vb.v4[1] = *(const half4*)(V + vcol * 128 + (cs1 << 3) + off);
                oacc[0][vt] = __builtin_amdgcn_mfma_f32_16x16x32_f16(
                    pa[0].v8, vb.v8, oacc[0][vt], 0, 0, 0);
                oacc[1][vt] = __builtin_amdgcn_mfma_f32_16x16x32_f16(
                    pa[1].v8, vb.v8, oacc[1][vt], 0, 0, 0);
            }
        }
        __builtin_amdgcn_s_setprio(0);
        cur ^= 1;
    }

    size_t obase = (size_t)blockIdx.y * N_WORDS;
    // lsum C-layout: row(qrow) = quad*4+r, col = lane&15 (all cols equal)
    if (lq == 0) {
#pragma unroll
        for (int qs = 0; qs < 2; ++qs)
#pragma unroll
            for (int r = 0; r < 4; ++r)
                pl[obase + mbase + qs * 16 + quad * 4 + r] = lacc[qs][r];
    }
#pragma unroll
    for (int qs = 0; qs < 2; ++qs)
#pragma unroll
        for (int vt = 0; vt < 4; ++vt)
#pragma unroll
            for (int r = 0; r < 4; ++r) {
                int row = mbase + qs * 16 + quad * 4 + r;
                pO[(obase + row) * 64 + vt * 16 + lq] = oacc[qs][vt][r];
            }
}

// ---------------------------------------------------------------------------
// Kernel 3: combine + output GEMM fused.
// Per block: reduce the S split partials for 16 rows directly into the
// transposed LDS tile (no head round-trip through HBM), then
// out = head @ w_o_eff  [8192x64]x[64x512] f32 on the vector ALU.
// ---------------------------------------------------------------------------
__global__ __launch_bounds__(256) void out_kernel(
    const float* __restrict__ pO, const float* __restrict__ pl,
    const float* __restrict__ we, float* __restrict__ out, int S)
{
    __shared__ __align__(16) float ldsHT[64 * 16];  // [k][row]
    int t = threadIdx.x;
    int r0 = blockIdx.x * 16;

    // combine: 16 rows x 64 dims, 4 values per thread, coalesced over d
#pragma unroll
    for (int j = 0; j < 4; ++j) {
        int i = t + j * 256;
        int row = i >> 6, d = i & 63;
        float so = 0.f, sl = 0.f;
        for (int s = 0; s < S; ++s) {
            so += pO[((size_t)s * N_WORDS + r0 + row) * 64 + d];
            sl += pl[(size_t)s * N_WORDS + r0 + row];
        }
        ldsHT[d * 16 + row] = so / sl;
    }
    __syncthreads();

    int w = t >> 6, l = t & 63;
    int cg = w & 1, rg = w >> 1;
    int j0 = cg * 256 + l * 4;

    float4 acc[8];
#pragma unroll
    for (int rr = 0; rr < 8; ++rr) acc[rr] = (float4){0.f, 0.f, 0.f, 0.f};

    for (int k = 0; k < 64; ++k) {
        float4 wv = *(const float4*)(we + (size_t)k * 512 + j0);
        float4 h0 = *(const float4*)(ldsHT + k * 16 + rg * 8);
        float4 h1 = *(const float4*)(ldsHT + k * 16 + rg * 8 + 4);
        float hr[8] = {h0.x, h0.y, h0.z, h0.w, h1.x, h1.y, h1.z, h1.w};
#pragma unroll
        for (int rr = 0; rr < 8; ++rr) {
            acc[rr].x = fmaf(hr[rr], wv.x, acc[rr].x);
            acc[rr].y = fmaf(hr[rr], wv.y, acc[rr].y);
            acc[rr].z = fmaf(hr[rr], wv.z, acc[rr].z);
            acc[rr].w = fmaf(hr[rr], wv.w, acc[rr].w);
        }
    }

#pragma unroll
    for (int rr = 0; rr < 8; ++rr) {
        int row = r0 + rg * 8 + rr;
        *(float4*)(out + (size_t)row * 512 + j0) = acc[rr];
    }
}

// ---------------------------------------------------------------------------
extern "C" void kernel_launch(void* const* d_in, const int* in_sizes, int n_in,
                              void* d_out, int out_size, void* d_ws, size_t ws_size,
                              hipStream_t stream)
{
    const float* x  = (const float*)d_in[0];
    const float* wq = (const float*)d_in[1];
    const float* wk = (const float*)d_in[2];
    const float* wv = (const float*)d_in[3];
    const float* wo = (const float*)d_in[4];
    float* out = (float*)d_out;

    char* ws = (char*)d_ws;
    unsigned short* qB = (unsigned short*)(ws);                    // 1 MB
    unsigned short* kB = (unsigned short*)(ws + 1048576);          // 1 MB
    unsigned short* vH = (unsigned short*)(ws + 2097152);          // 1 MB
    float* we   = (float*)(ws + 3145728);                          // 128 KB
    float* pl   = (float*)(ws + 5373952);                          // <=256 KB
    float* pO   = (float*)(ws + 5636096);                          // S * 2 MB

    // S splits: 8 if workspace allows (22.4 MB), else 4 (13.3 MB, known-safe)
    int S = (ws_size >= (size_t)(5636096) + 8u * 2097152u) ? 8 : 4;
    int nk = N_WORDS / S;

    hipLaunchKernelGGL(qkv_gemm, dim3(128, 4), dim3(256), 0, stream,
                       x, wq, wk, wv, wo, qB, kB, vH, we);
    hipLaunchKernelGGL(attn_kernel, dim3(64, S), dim3(256), 0, stream,
                       qB, kB, vH, pO, pl, nk);
    hipLaunchKernelGGL(out_kernel, dim3(512), dim3(256), 0, stream,
                       pO, pl, we, out, S);
}

// Round 3
// 130.269 us; speedup vs baseline: 1.0525x; 1.0120x over previous
//
#include <hip/hip_runtime.h>
#include <stdint.h>

#define N_WORDS 8192
#define LOG2E_8 0.18033688011112043f   // log2(e)/sqrt(64)

typedef __attribute__((ext_vector_type(8))) short short8;
typedef __attribute__((ext_vector_type(4))) float f32x4;
typedef __attribute__((ext_vector_type(2))) __fp16 pkhalf2;   // cvt_pkrtz return type
typedef __attribute__((ext_vector_type(4))) _Float16 half4;
typedef __attribute__((ext_vector_type(8))) _Float16 half8;

__device__ __forceinline__ unsigned short f32_to_bf16(float f) {
    union { float f; unsigned u; } v; v.f = f;
    unsigned u = v.u;
    return (unsigned short)((u + 0x7FFFu + ((u >> 16) & 1u)) >> 16);
}

__device__ __forceinline__ unsigned short f32_to_f16(float f) {
    union { _Float16 h; unsigned short u; } cv;
    cv.h = (_Float16)f;
    return cv.u;
}

// global -> LDS direct copy, 16B per lane. LDS dest must be wave-uniform base;
// HW adds lane*16. Global ptr is per-lane.
__device__ __forceinline__ void async16(const void* g, void* l) {
    __builtin_amdgcn_global_load_lds(
        (const __attribute__((address_space(1))) unsigned int*)g,
        (__attribute__((address_space(3))) unsigned int*)l, 16, 0, 0);
}

// ---------------------------------------------------------------------------
// Kernel 1: QKV projection as bf16 MFMA GEMM: [8192x512] @ [512x64] x3 mats,
// plus (blockIdx.y==3) the w_o_eff fold:
//   weT[j][p] = (f16) sum_h wo[h*64+p][j]   (transposed, B-frag ready)
// grid (128, 4), 256 thr -> exactly 512 blocks = 2/CU.
// Register-prefetch pipeline: global loads for tile kb+1 issued while MFMAs
// of tile kb run.
// Outputs:
//   mat0 -> qB bf16 [row][64], cols XOR-swizzled in 8-elem chunks, pre-scaled
//           by log2e/8 (folds softmax scale + exp2 base change)
//   mat1 -> kB bf16, same swizzle
//   mat2 -> vH f16 [vcol][8192], rows swizzled per 64-row group
// Swizzle: chunk c (8 elems) of row r stored at position c ^ (r&7).
// ---------------------------------------------------------------------------
__global__ __launch_bounds__(256) void qkv_gemm(
    const float* __restrict__ x,
    const float* __restrict__ wq, const float* __restrict__ wk,
    const float* __restrict__ wv, const float* __restrict__ wo,
    unsigned short* __restrict__ qB, unsigned short* __restrict__ kB,
    unsigned short* __restrict__ vH, unsigned short* __restrict__ weT)
{
    int t = threadIdx.x;
    int mat = blockIdx.y;

    if (mat == 3) {
        // w_o_eff fold: coalesced reads over j; f16 transposed scatter store
        int i = blockIdx.x * 256 + t;
        int p = i >> 9;
        int j = i & 511;
        float s = 0.0f;
#pragma unroll
        for (int h = 0; h < 8; ++h) s += wo[(size_t)(h * 64 + p) * 512 + j];
        weT[(size_t)j * 64 + p] = f32_to_f16(s);
        return;
    }

    __shared__ __align__(16) unsigned short ldsX[64 * 72];  // [m][k] pitch 72
    __shared__ __align__(16) unsigned short ldsW[64 * 72];  // [n][k] pitch 72

    int mt = blockIdx.x;
    const float* w = (mat == 0) ? wq : (mat == 1) ? wk : wv;

    int wvid = t >> 6, lane = t & 63;
    int lq = lane & 15, quad = lane >> 4;

    f32x4 acc[4];
#pragma unroll
    for (int nt = 0; nt < 4; ++nt) acc[nt] = (f32x4){0.f, 0.f, 0.f, 0.f};

    // prefetch registers
    float4 xr[4];
    float wr[16];
    int wn = t & 63, wkbs = (t >> 6) * 16;

    // prologue: load tile kb=0
    {
        int k0 = 0;
#pragma unroll
        for (int j2 = 0; j2 < 4; ++j2) {
            int i = t + j2 * 256;
            int row = i >> 4, c4 = (i & 15) * 4;
            xr[j2] = *(const float4*)(x + (size_t)(mt * 64 + row) * 512 + k0 + c4);
        }
#pragma unroll
        for (int kk = 0; kk < 16; ++kk)
            wr[kk] = w[(size_t)(k0 + wkbs + kk) * 64 + wn];
    }

    for (int kb = 0; kb < 8; ++kb) {
        __syncthreads();   // all waves finished reading LDS of previous tile
        // store prefetched registers -> LDS (f32 -> bf16)
#pragma unroll
        for (int j2 = 0; j2 < 4; ++j2) {
            int i = t + j2 * 256;
            int row = i >> 4, c4 = (i & 15) * 4;
            unsigned p0 = f32_to_bf16(xr[j2].x) | ((unsigned)f32_to_bf16(xr[j2].y) << 16);
            unsigned p1 = f32_to_bf16(xr[j2].z) | ((unsigned)f32_to_bf16(xr[j2].w) << 16);
            *(uint2*)(&ldsX[row * 72 + c4]) = make_uint2(p0, p1);
        }
#pragma unroll
        for (int kk = 0; kk < 16; kk += 2) {
            unsigned p = f32_to_bf16(wr[kk]) | ((unsigned)f32_to_bf16(wr[kk + 1]) << 16);
            *(unsigned*)(&ldsW[wn * 72 + wkbs + kk]) = p;
        }
        __syncthreads();

        // issue next tile's global loads early; they complete under the MFMAs
        if (kb < 7) {
            int k0 = (kb + 1) * 64;
#pragma unroll
            for (int j2 = 0; j2 < 4; ++j2) {
                int i = t + j2 * 256;
                int row = i >> 4, c4 = (i & 15) * 4;
                xr[j2] = *(const float4*)(x + (size_t)(mt * 64 + row) * 512 + k0 + c4);
            }
#pragma unroll
            for (int kk = 0; kk < 16; ++kk)
                wr[kk] = w[(size_t)(k0 + wkbs + kk) * 64 + wn];
        }

        int m = wvid * 16 + lq;
        short8 a0 = *(const short8*)(&ldsX[m * 72 + quad * 8]);
        short8 a1 = *(const short8*)(&ldsX[m * 72 + 32 + quad * 8]);
#pragma unroll
        for (int nt = 0; nt < 4; ++nt) {
            short8 b0 = *(const short8*)(&ldsW[(nt * 16 + lq) * 72 + quad * 8]);
            short8 b1 = *(const short8*)(&ldsW[(nt * 16 + lq) * 72 + 32 + quad * 8]);
            acc[nt] = __builtin_amdgcn_mfma_f32_16x16x32_bf16(a0, b0, acc[nt], 0, 0, 0);
            acc[nt] = __builtin_amdgcn_mfma_f32_16x16x32_bf16(a1, b1, acc[nt], 0, 0, 0);
        }
    }

    int mrow_base = mt * 64 + wvid * 16;
#pragma unroll
    for (int nt = 0; nt < 4; ++nt) {
#pragma unroll
        for (int r = 0; r < 4; ++r) {
            int row = mrow_base + quad * 4 + r;
            int n = nt * 16 + lq;
            float v = acc[nt][r];
            if (mat == 0) {
                v *= LOG2E_8;
                int col = ((((n >> 3) ^ (row & 7)) << 3)) | (n & 7);
                qB[(size_t)row * 64 + col] = f32_to_bf16(v);
            } else if (mat == 1) {
                int col = ((((n >> 3) ^ (row & 7)) << 3)) | (n & 7);
                kB[(size_t)row * 64 + col] = f32_to_bf16(v);
            } else {
                int rs = (row & ~63) | (((((row >> 3) & 7) ^ (n & 7)) << 3)) | (row & 7);
                vH[(size_t)n * N_WORDS + rs] = f32_to_f16(v);
            }
        }
    }
}

// ---------------------------------------------------------------------------
// Kernel 2: fixed-max flash attention partials.
// grid (64 q-blocks of 128 rows, S splits), 256 thr = 4 waves x 32 qrows.
// Double-buffered K/V staging; compute is MATRIX-PIPE bound (~2800 cyc/tile/CU
// vs ~1560 VALU), so lsum moved OFF the MFMA pipe onto the slack VALU
// (8 f32 adds/qs/u + 2 shfl_xor epilogue) -- removes 8 of 72 MFMAs/tile.
// PV uses 16x16x32 f16 (K=32) with the permuted logical-k mapping (see R2).
// Partial O stored as f16 (values |O| < ~40, f16-safe; halves pO traffic).
// ---------------------------------------------------------------------------
__global__ __launch_bounds__(256) void attn_kernel(
    const unsigned short* __restrict__ qB,
    const unsigned short* __restrict__ kB,
    const unsigned short* __restrict__ vH,
    unsigned short* __restrict__ pOh, float* __restrict__ pl, int nk)
{
    __shared__ __align__(16) unsigned short ldsK[2][128 * 64];
    __shared__ __align__(16) unsigned short ldsV[2][64 * 128];

    int t = threadIdx.x;
    int wvid = t >> 6, lane = t & 63;
    int lq = lane & 15, quad = lane >> 4;
    int mbase = blockIdx.x * 128 + wvid * 32;
    int n0 = blockIdx.y * nk;

    // Q fragments for 2 q-subtiles (rows mbase+lq, mbase+16+lq)
    short8 qf[2][2];
#pragma unroll
    for (int qs = 0; qs < 2; ++qs) {
        int row = mbase + qs * 16 + lq;
        const unsigned short* qr = qB + (size_t)row * 64;
        int s7 = row & 7;
        qf[qs][0] = *(const short8*)(qr + ((quad ^ s7) << 3));
        qf[qs][1] = *(const short8*)(qr + (((4 + quad) ^ s7) << 3));
    }

    f32x4 oacc[2][4];
#pragma unroll
    for (int qs = 0; qs < 2; ++qs)
#pragma unroll
        for (int vt = 0; vt < 4; ++vt) oacc[qs][vt] = (f32x4){0.f, 0.f, 0.f, 0.f};
    float lsum0 = 0.f, lsum1 = 0.f;

    auto stage = [&](int buf, int nb) {
        // K tile: 16KB contiguous in global (swizzle baked in)
        const char* gK = (const char*)kB + (size_t)nb * 128;
#pragma unroll
        for (int i = 0; i < 4; ++i) {
            int L0 = (wvid * 4 + i) * 64;
            async16(gK + (size_t)(L0 + lane) * 16, (char*)ldsK[buf] + (size_t)L0 * 16);
        }
        // V tile: 64 vcols x 128 krows (2 chunk-groups per vcol)
#pragma unroll
        for (int i = 0; i < 4; ++i) {
            int L0 = (wvid * 4 + i) * 64;
            int L = L0 + lane;
            int vcol = L >> 4, ct = L & 15;
            const char* src = (const char*)vH + (size_t)vcol * 16384 +
                              (size_t)nb * 2 + ((ct >> 3) << 7) + ((ct & 7) << 4);
            async16(src, (char*)ldsV[buf] + (size_t)L0 * 16);
        }
    };

    int tiles = nk >> 7;
    stage(0, n0);
    int cur = 0;

    for (int tt = 0; tt < tiles; ++tt) {
        __syncthreads();   // vmcnt(0) drain + barrier: buf[cur] ready,
                           // everyone done reading buf[cur^1]
        if (tt + 1 < tiles) stage(cur ^ 1, n0 + (tt + 1) * 128);

        __builtin_amdgcn_s_setprio(1);
        const unsigned short* K = ldsK[cur];
        const unsigned short* V = ldsV[cur];

#pragma unroll
        for (int u = 0; u < 4; ++u) {
            // S^T for the two 16-krow halves of this 32-krow pair
            f32x4 st[2][2];   // [h][qs]
#pragma unroll
            for (int h = 0; h < 2; ++h) {
                int nt = 2 * u + h;
                int s7 = lq & 7;
                const unsigned short* kr = K + (nt * 16 + lq) * 64;
                short8 a0 = *(const short8*)(kr + ((quad ^ s7) << 3));
                short8 a1 = *(const short8*)(kr + (((4 + quad) ^ s7) << 3));
                f32x4 s0 = (f32x4){0.f, 0.f, 0.f, 0.f};
                f32x4 s1 = (f32x4){0.f, 0.f, 0.f, 0.f};
                s0 = __builtin_amdgcn_mfma_f32_16x16x32_bf16(a0, qf[0][0], s0, 0, 0, 0);
                s0 = __builtin_amdgcn_mfma_f32_16x16x32_bf16(a1, qf[0][1], s0, 0, 0, 0);
                s1 = __builtin_amdgcn_mfma_f32_16x16x32_bf16(a0, qf[1][0], s1, 0, 0, 0);
                s1 = __builtin_amdgcn_mfma_f32_16x16x32_bf16(a1, qf[1][1], s1, 0, 0, 0);
                st[h][0] = s0;
                st[h][1] = s1;
            }

            // p = exp2(s); lsum on the VALU (matrix pipe is the bottleneck)
            union { half8 v8; pkhalf2 v2[4]; } pa[2];
#pragma unroll
            for (int h = 0; h < 2; ++h) {
                float e0 = exp2f(st[h][0][0]);
                float e1 = exp2f(st[h][0][1]);
                float e2 = exp2f(st[h][0][2]);
                float e3 = exp2f(st[h][0][3]);
                lsum0 += (e0 + e1) + (e2 + e3);
                pa[0].v2[h * 2 + 0] = __builtin_amdgcn_cvt_pkrtz(e0, e1);
                pa[0].v2[h * 2 + 1] = __builtin_amdgcn_cvt_pkrtz(e2, e3);
                float f0 = exp2f(st[h][1][0]);
                float f1 = exp2f(st[h][1][1]);
                float f2 = exp2f(st[h][1][2]);
                float f3 = exp2f(st[h][1][3]);
                lsum1 += (f0 + f1) + (f2 + f3);
                pa[1].v2[h * 2 + 0] = __builtin_amdgcn_cvt_pkrtz(f0, f1);
                pa[1].v2[h * 2 + 1] = __builtin_amdgcn_cvt_pkrtz(f2, f3);
            }

            // PV: one K=32 f16 MFMA per (qs, vt) covering both 16-krow halves
            int ct0 = 4 * u + (quad >> 1);
            int off = (quad & 1) * 4;
#pragma unroll
            for (int vt = 0; vt < 4; ++vt) {
                int vcol = vt * 16 + lq;
                int cs0 = (ct0 & 8) | ((ct0 & 7) ^ (vcol & 7));
                int ct1 = ct0 + 2;
                int cs1 = (ct1 & 8) | ((ct1 & 7) ^ (vcol & 7));
                union { half8 v8; half4 v4[2]; } vb;
                vb.v4[0] = *(const half4*)(V + vcol * 128 + (cs0 << 3) + off);
                vb.v4[1] = *(const half4*)(V + vcol * 128 + (cs1 << 3) + off);
                oacc[0][vt] = __builtin_amdgcn_mfma_f32_16x16x32_f16(
                    pa[0].v8, vb.v8, oacc[0][vt], 0, 0, 0);
                oacc[1][vt] = __builtin_amdgcn_mfma_f32_16x16x32_f16(
                    pa[1].v8, vb.v8, oacc[1][vt], 0, 0, 0);
            }
        }
        __builtin_amdgcn_s_setprio(0);
        cur ^= 1;
    }

    // lsum covers qrow=lq for this wave's quad-slice of krows; reduce quads
    lsum0 += __shfl_xor(lsum0, 16); lsum0 += __shfl_xor(lsum0, 32);
    lsum1 += __shfl_xor(lsum1, 16); lsum1 += __shfl_xor(lsum1, 32);

    size_t obase = (size_t)blockIdx.y * N_WORDS;
    if (quad == 0) {
        pl[obase + mbase + lq] = lsum0;
        pl[obase + mbase + 16 + lq] = lsum1;
    }
#pragma unroll
    for (int qs = 0; qs < 2; ++qs)
#pragma unroll
        for (int vt = 0; vt < 4; ++vt)
#pragma unroll
            for (int r = 0; r < 4; ++r) {
                int row = mbase + qs * 16 + quad * 4 + r;
                pOh[(obase + row) * 64 + vt * 16 + lq] = f32_to_f16(oacc[qs][vt][r]);
            }
}

// ---------------------------------------------------------------------------
// Kernel 3: combine + output GEMM fused, GEMM on the MFMA pipe.
// Per block (16 rows): reduce the S split partials (f16 in, f32 accum) into a
// padded f16 LDS tile, then out = head @ weT via 16x16x32 f16 MFMA
// (A = head rows from LDS; B = weT streamed from L2, 64KB, shared by all
// blocks). Replaces 2048 scalar v_fma_f32/thread (~5.2us chip-wide) with
// 16 MFMAs/wave (~0.3us).
// ---------------------------------------------------------------------------
__global__ __launch_bounds__(256) void out_kernel(
    const unsigned short* __restrict__ pOh, const float* __restrict__ pl,
    const unsigned short* __restrict__ weT, float* __restrict__ out, int S)
{
    __shared__ __align__(16) _Float16 ldsH[16 * 72];  // [row][k] pitch 72
    int t = threadIdx.x;
    int r0 = blockIdx.x * 16;
    const _Float16* pOf = (const _Float16*)pOh;

    // combine: 16 rows x 64 dims; per wave: row fixed, d = lane (coalesced)
#pragma unroll
    for (int j = 0; j < 4; ++j) {
        int i = t + j * 256;
        int row = i >> 6, d = i & 63;
        float so = 0.f, sl = 0.f;
        for (int s = 0; s < S; ++s) {
            so += (float)pOf[((size_t)s * N_WORDS + r0 + row) * 64 + d];
            sl += pl[(size_t)s * N_WORDS + r0 + row];
        }
        ldsH[row * 72 + d] = (_Float16)(so / sl);
    }
    __syncthreads();

    int wv = t >> 6, lane = t & 63;
    int lq = lane & 15, quad = lane >> 4;

    // A-frag: head row = lq, k = quad*8+j (+32 for a1)
    half8 a0 = *(const half8*)(&ldsH[lq * 72 + quad * 8]);
    half8 a1 = *(const half8*)(&ldsH[lq * 72 + 32 + quad * 8]);
    const _Float16* wT = (const _Float16*)weT;

#pragma unroll
    for (int ntl = 0; ntl < 8; ++ntl) {
        int nt = wv * 8 + ntl;
        const _Float16* wrow = wT + (size_t)(nt * 16 + lq) * 64;
        half8 b0 = *(const half8*)(wrow + quad * 8);
        half8 b1 = *(const half8*)(wrow + 32 + quad * 8);
        f32x4 acc = (f32x4){0.f, 0.f, 0.f, 0.f};
        acc = __builtin_amdgcn_mfma_f32_16x16x32_f16(a0, b0, acc, 0, 0, 0);
        acc = __builtin_amdgcn_mfma_f32_16x16x32_f16(a1, b1, acc, 0, 0, 0);
#pragma unroll
        for (int r = 0; r < 4; ++r)
            out[(size_t)(r0 + quad * 4 + r) * 512 + nt * 16 + lq] = acc[r];
    }
}

// ---------------------------------------------------------------------------
extern "C" void kernel_launch(void* const* d_in, const int* in_sizes, int n_in,
                              void* d_out, int out_size, void* d_ws, size_t ws_size,
                              hipStream_t stream)
{
    const float* x  = (const float*)d_in[0];
    const float* wq = (const float*)d_in[1];
    const float* wk = (const float*)d_in[2];
    const float* wv = (const float*)d_in[3];
    const float* wo = (const float*)d_in[4];
    float* out = (float*)d_out;

    char* ws = (char*)d_ws;
    unsigned short* qB  = (unsigned short*)(ws);                   // 1 MB
    unsigned short* kB  = (unsigned short*)(ws + 1048576);         // 1 MB
    unsigned short* vH  = (unsigned short*)(ws + 2097152);         // 1 MB
    unsigned short* weT = (unsigned short*)(ws + 3145728);         // 64 KB
    float* pl           = (float*)(ws + 3211264);                  // S*32 KB
    unsigned short* pOh = (unsigned short*)(ws + 3473408);         // S*1 MB

    // S splits: 8 if workspace allows (~11.9 MB), else 4
    int S = (ws_size >= (size_t)3473408 + 8u * 1048576u) ? 8 : 4;
    int nk = N_WORDS / S;

    hipLaunchKernelGGL(qkv_gemm, dim3(128, 4), dim3(256), 0, stream,
                       x, wq, wk, wv, wo, qB, kB, vH, weT);
    hipLaunchKernelGGL(attn_kernel, dim3(64, S), dim3(256), 0, stream,
                       qB, kB, vH, pOh, pl, nk);
    hipLaunchKernelGGL(out_kernel, dim3(512), dim3(256), 0, stream,
                       pOh, pl, weT, out, S);
}